// Round 13
// baseline (324.984 us; speedup 1.0000x reference)
//
#include <hip/hip_runtime.h>

#define NND 50000
#define NE  800000
#define CF  128
#define NGR 512
#define DCAP 64   // per-node CSR slot capacity (Poisson(16); max deg ~38)

typedef __bf16 bf16;
typedef __bf16 bf16x2 __attribute__((ext_vector_type(2)));
typedef __bf16 bf16x4 __attribute__((ext_vector_type(4)));
typedef __bf16 bf16x8 __attribute__((ext_vector_type(8)));
typedef float  f32x4  __attribute__((ext_vector_type(4)));

// ---------------- zero cnt: 12544 int4 = 200704B >= 200000B ----------------
__global__ __launch_bounds__(256) void zero_k(int4* __restrict__ p) {
  p[blockIdx.x * 256 + threadIdx.x] = int4{0, 0, 0, 0};   // 49 blocks x 256
}

// ---- fused {x->bf16, weights->bf16 TRANSPOSED+SWIZZLED, graph boundaries} + {CSR fill} ----
// Weight layout written here IS the final LDS byte layout of the gemm B^T tile:
// per matrix m: elem (k,n) -> m*16384 + n*128 + (((k>>3)^(n&15))<<3) + (k&7).
// Blocks 0..6249: conv work. Blocks 6250..9377: 8-class dst-confined CSR fill
// (all writers of a csr line on one XCD; nt-stores measured WORSE in round 9).
__global__ __launch_bounds__(256) void convfill_k(const float* __restrict__ x,
                                                  bf16* __restrict__ xb,
                                                  const float* __restrict__ w1l, const float* __restrict__ w1r,
                                                  const float* __restrict__ w2l, const float* __restrict__ w2r,
                                                  const float* __restrict__ w3l, const float* __restrict__ w3r,
                                                  bf16* __restrict__ wb,
                                                  const int* __restrict__ batch,
                                                  int* __restrict__ gs,
                                                  const int* __restrict__ src,
                                                  const int* __restrict__ dst,
                                                  int* __restrict__ cnt,
                                                  unsigned short* __restrict__ csr) {
  if (blockIdx.x < 6250) {
    int t = blockIdx.x * 256 + threadIdx.x;   // t < 1,600,000 = NND*CF/4
    {
      f32x4 v = ((const f32x4*)x)[t];
      bf16x4 o;
      o[0] = (bf16)v[0]; o[1] = (bf16)v[1]; o[2] = (bf16)v[2]; o[3] = (bf16)v[3];
      ((bf16x4*)xb)[t] = o;
    }
    if (t < 49152) {  // 6 matrices x 16384 elems, 2 per thread
      int m = t >> 13, w2i = t & 8191;
      const float* sp = (m == 0) ? w1l : (m == 1) ? w1r : (m == 2) ? w2l
                      : (m == 3) ? w2r : (m == 4) ? w3l : w3r;
      int e0 = w2i * 2;
      int k = e0 >> 7, n = e0 & 127;          // source w[k][n], n even
      float2 v = *(const float2*)(sp + e0);
      bf16* wm = wb + m * 16384;
      wm[n * 128       + ((((k >> 3) ^ (n       & 15)) << 3)) + (k & 7)] = (bf16)v.x;
      wm[(n + 1) * 128 + ((((k >> 3) ^ ((n + 1) & 15)) << 3)) + (k & 7)] = (bf16)v.y;
    }
    if (t < NND) {
      int b = batch[t];
      if (t == 0) {
        for (int g = 0; g <= b; g++) gs[g] = 0;
      } else {
        int pb = batch[t - 1];
        for (int g = pb + 1; g <= b; g++) gs[g] = t;
      }
      if (t == NND - 1) {
        for (int g = b + 1; g <= NGR; g++) gs[g] = NND;
      }
    }
  } else {
    int bb = blockIdx.x - 6250;               // 3128 fill blocks = 391 chunks x 8 classes
    int r  = bb & 7;
    int lo = r * 6250, hi = lo + 6250;
    int ebase = (bb >> 3) * 2048;
#pragma unroll
    for (int h = 0; h < 2; h++) {
      int e = ebase + h * 1024 + threadIdx.x * 4;
      if (e < NE) {                            // NE % 4 == 0 -> full int4 in bounds
        int4 d4 = *(const int4*)(dst + e);
        int4 s4 = *(const int4*)(src + e);
        int dd[4] = {d4.x, d4.y, d4.z, d4.w};
        int ss[4] = {s4.x, s4.y, s4.z, s4.w};
#pragma unroll
        for (int u = 0; u < 4; u++) {
          int d = dd[u];
          if (d >= lo && d < hi) {
            int p = atomicAdd(&cnt[d], 1);
            if (p < DCAP) csr[d * DCAP + p] = (unsigned short)ss[u];
          }
        }
      }
    }
  }
}

// ------ fused in-register mean-aggregate + [agg|prev]@[wl;wr] + b, ReLU, (+prev), LN ------
// Block = 256 thr (4 waves) x 64 rows; wave = 16 rows. Lane (q=lane>>4, r=lane&15) owns
// row wrow+r and features {q*8 + 32*kk}, kk<4 -> gathers DIRECTLY into its phase-0
// A-fragment (no agg tensor, no extra dispatch). 4 q-lanes/row read the full 256B
// neighbor row per edge. 2-edge ILP batches: 8 x 16B loads in flight per lane.
// 32KB LDS + ~96 VGPR -> 5 blocks/CU (20 waves/CU) = 2.5x round-2's failed fusion.
// All 782 blocks co-resident -> one scheduling wave per layer.
template <typename TO>
__global__ __launch_bounds__(256, 5) void aggemm_k(
    const bf16* __restrict__ xp,     // prev-layer features: gather source AND lin_r input
    const int* __restrict__ cnt, const unsigned short* __restrict__ csr,
    const bf16* __restrict__ wswz,   // wl,wr pre-swizzled, 16384 elems each
    const float* __restrict__ bias, const float* __restrict__ gamma,
    const float* __restrict__ beta, TO* __restrict__ outp, int addres) {
  __shared__ bf16 bt[16384];   // 32KB
  int tid = threadIdx.x;
  int lane = tid & 63;
  int wave = tid >> 6;
  int q = lane >> 4, r = lane & 15;
  int wrow = blockIdx.x * 64 + wave * 16;
  int arow = min(wrow + r, NND - 1);   // clamped; OOB rows never stored

  // stage phase-0 tile (wl), linear copy of pre-swizzled bytes
  {
    const bf16x8* g = (const bf16x8*)wswz;
#pragma unroll
    for (int i = 0; i < 8; i++)
      ((bf16x8*)bt)[tid + i * 256] = g[tid + i * 256];
  }
  // prefetch phase-1 A-fragments (lin_r reads own row) -- in flight during gather
  bf16x8 af1[4];
  {
    const bf16* a1 = xp + arow * 128 + q * 8;
#pragma unroll
    for (int kk = 0; kk < 4; kk++) af1[kk] = *(const bf16x8*)(a1 + kk * 32);
  }

  // ---- in-register mean aggregation for row arow, feature quarter q ----
  int deg = min(cnt[arow], DCAP);
  const unsigned short* cp = csr + arow * DCAP;
  const bf16* xq = xp + q * 8;
  float fa[4][8] = {};
  int e = 0;
  for (; e + 2 <= deg; e += 2) {       // 2-edge ILP: 8 x 16B loads in flight
    ushort2 ss = *(const ushort2*)(cp + e);
    const bf16* p0 = xq + (int)ss.x * 128;
    const bf16* p1 = xq + (int)ss.y * 128;
    bf16x8 v0[4], v1[4];
#pragma unroll
    for (int kk = 0; kk < 4; kk++) {
      v0[kk] = *(const bf16x8*)(p0 + kk * 32);
      v1[kk] = *(const bf16x8*)(p1 + kk * 32);
    }
#pragma unroll
    for (int kk = 0; kk < 4; kk++)
#pragma unroll
      for (int j = 0; j < 8; j++)
        fa[kk][j] += (float)v0[kk][j] + (float)v1[kk][j];
  }
  if (e < deg) {                       // odd tail
    const bf16* p0 = xq + (int)cp[e] * 128;
#pragma unroll
    for (int kk = 0; kk < 4; kk++) {
      bf16x8 vt = *(const bf16x8*)(p0 + kk * 32);
#pragma unroll
      for (int j = 0; j < 8; j++) fa[kk][j] += (float)vt[j];
    }
  }
  bf16x8 af0[4];
  {
    float inv = 1.0f / fmaxf((float)deg, 1.0f);
#pragma unroll
    for (int kk = 0; kk < 4; kk++) {
      bf16x8 o;
#pragma unroll
      for (int j = 0; j < 8; j++) o[j] = (bf16)(fa[kk][j] * inv);
      af0[kk] = o;
    }
  }
  __syncthreads();   // bt (wl) ready

  f32x4 acc[8] = {};
#pragma unroll
  for (int kk = 0; kk < 4; kk++) {
#pragma unroll
    for (int t = 0; t < 8; t++) {
      int n = t * 16 + r;
      bf16x8 bfrag = *(const bf16x8*)&bt[n * 128 + (((kk * 4 + q) ^ (n & 15)) << 3)];
      acc[t] = __builtin_amdgcn_mfma_f32_16x16x32_bf16(af0[kk], bfrag, acc[t], 0, 0, 0);
    }
  }
  __syncthreads();   // phase-0 readers done
  {
    const bf16x8* g = (const bf16x8*)(wswz + 16384);
#pragma unroll
    for (int i = 0; i < 8; i++)
      ((bf16x8*)bt)[tid + i * 256] = g[tid + i * 256];
  }
  __syncthreads();
#pragma unroll
  for (int kk = 0; kk < 4; kk++) {
#pragma unroll
    for (int t = 0; t < 8; t++) {
      int n = t * 16 + r;
      bf16x8 bfrag = *(const bf16x8*)&bt[n * 128 + (((kk * 4 + q) ^ (n & 15)) << 3)];
      acc[t] = __builtin_amdgcn_mfma_f32_16x16x32_bf16(af1[kk], bfrag, acc[t], 0, 0, 0);
    }
  }

  float biasf[8], gf[8], bef[8];
#pragma unroll
  for (int t = 0; t < 8; t++) {
    int c = t * 16 + r;
    biasf[t] = bias[c];
    gf[t]    = gamma[c];
    bef[t]   = beta[c];
  }

#pragma unroll
  for (int reg = 0; reg < 4; reg++) {
    int row = wrow + q * 4 + reg;
    int rr  = (row < NND) ? row : (NND - 1);
    const bf16* prow = xp + rr * 128;
    float vals[8];
    float s = 0.f, s2 = 0.f;
#pragma unroll
    for (int t = 0; t < 8; t++) {
      float v = acc[t][reg] + biasf[t];
      v = fmaxf(v, 0.f);
      if (addres) v += (float)prow[t * 16 + r];
      vals[t] = v;
      s += v;
      s2 += v * v;
    }
#pragma unroll
    for (int m = 1; m < 16; m <<= 1) {
      s  += __shfl_xor(s, m);
      s2 += __shfl_xor(s2, m);
    }
    float mean = s * (1.f / 128.f);
    float var  = fmaxf(s2 * (1.f / 128.f) - mean * mean, 0.f);
    float rstd = rsqrtf(var + 1e-5f);
    if (row < NND) {
      TO* orow = outp + row * 128;
#pragma unroll
      for (int t = 0; t < 8; t++)
        orow[t * 16 + r] = (TO)((vals[t] - mean) * rstd * gf[t] + bef[t]);
    }
  }
}

// ---------------- fused mean-pool + head (sorted batch, no atomics) ----------------
__global__ __launch_bounds__(256) void poolhead_k(
    const float* __restrict__ h3, const int* __restrict__ gs,
    const float* __restrict__ wc, const float* __restrict__ bc,
    float* __restrict__ outv, float* __restrict__ avgv) {
  int g = blockIdx.x;
  int s = gs[g], epos = gs[g + 1];
  int tid = threadIdx.x;
  int wave = tid >> 6, lane = tid & 63;
  float a0 = 0.f, a1 = 0.f;
  for (int row = s + wave; row < epos; row += 4) {
    float2 v = *(const float2*)(h3 + row * 128 + 2 * lane);
    a0 += v.x; a1 += v.y;
  }
  __shared__ float red[4][128];
  red[wave][2 * lane]     = a0;
  red[wave][2 * lane + 1] = a1;
  __syncthreads();
  __shared__ float sp[4];
  if (tid < 128) {
    float t4  = red[0][tid] + red[1][tid] + red[2][tid] + red[3][tid];
    float inv = 1.f / fmaxf((float)(epos - s), 1.f);
    float avg = t4 * inv;
    avgv[g * 128 + tid] = avg;
    float p0 = avg * wc[tid * 2 + 0];
    float p1 = avg * wc[tid * 2 + 1];
#pragma unroll
    for (int m = 1; m < 64; m <<= 1) {
      p0 += __shfl_xor(p0, m);
      p1 += __shfl_xor(p1, m);
    }
    if ((tid & 63) == 0) {
      sp[(tid >> 6) * 2]     = p0;
      sp[(tid >> 6) * 2 + 1] = p1;
    }
  }
  __syncthreads();
  if (tid == 0) {
    outv[g * 2 + 0] = sp[0] + sp[2] + bc[0];
    outv[g * 2 + 1] = sp[1] + sp[3] + bc[1];
  }
}

extern "C" void kernel_launch(void* const* d_in, const int* in_sizes, int n_in,
                              void* d_out, int out_size, void* d_ws, size_t ws_size,
                              hipStream_t stream) {
  const float* x   = (const float*)d_in[0];
  const int* ei    = (const int*)d_in[1];
  const int* batch = (const int*)d_in[2];
  const float* w1l = (const float*)d_in[3],  *w1r = (const float*)d_in[4];
  const float* b1  = (const float*)d_in[5],  *g1  = (const float*)d_in[6],  *be1 = (const float*)d_in[7];
  const float* w2l = (const float*)d_in[8],  *w2r = (const float*)d_in[9];
  const float* b2  = (const float*)d_in[10], *g2  = (const float*)d_in[11], *be2 = (const float*)d_in[12];
  const float* w3l = (const float*)d_in[13], *w3r = (const float*)d_in[14];
  const float* b3  = (const float*)d_in[15], *g3  = (const float*)d_in[16], *be3 = (const float*)d_in[17];
  const float* wc  = (const float*)d_in[18], *bc  = (const float*)d_in[19];
  const int* srcv = ei;
  const int* dstv = ei + NE;

  char* base = (char*)d_ws;
  int*            cnt  = (int*)(base + 0);          // 200000 (zeroed by zero_k, pad to 200704)
  int*            gs   = (int*)(base + 200704);     // 2052
  bf16*           wb   = (bf16*)(base + 204800);    // 196608 (6 x 128x128 bf16, pre-swizzled)
  unsigned short* csr  = (unsigned short*)(base + 401408);  // 6.4 MB (50000 x 64 u16 slots)
  bf16*           h1   = (bf16*)(base + 19601408);  // 12.8 MB
  bf16*           h2xb = (bf16*)(base + 32401408);  // 12.8 MB: xb until layer1 consumes, then h2

  float* outv = (float*)d_out;             // 1024
  float* h3   = outv + 1024;               // 50000*128
  float* avgv = outv + 1024 + NND * CF;    // 512*128

  zero_k<<<49, 256, 0, stream>>>((int4*)base);
  convfill_k<<<9378, 256, 0, stream>>>(x, h2xb, w1l, w1r, w2l, w2r, w3l, w3r, wb,
                                       batch, gs, srcv, dstv, cnt, csr);

  // layer 1 (xb aliases h2xb; dead after layer-2 overwrites it)
  aggemm_k<bf16><<<782, 256, 0, stream>>>(h2xb, cnt, csr, wb,           b1, g1, be1, h1, 0);
  // layer 2
  aggemm_k<bf16><<<782, 256, 0, stream>>>(h1, cnt, csr, wb + 2 * 16384, b2, g2, be2, h2xb, 1);
  // layer 3
  aggemm_k<float><<<782, 256, 0, stream>>>(h2xb, cnt, csr, wb + 4 * 16384, b3, g3, be3, h3, 1);
  // pool + head
  poolhead_k<<<NGR, 256, 0, stream>>>(h3, gs, wc, bc, outv, avgv);
}

// Round 14
// 290.242 us; speedup vs baseline: 1.1197x; 1.1197x over previous
//
#include <hip/hip_runtime.h>

#define NND 50000
#define NE  800000
#define CF  128
#define NGR 512
#define DCAP 64   // per-node CSR slot capacity (Poisson(16); max deg ~38)

typedef __bf16 bf16;
typedef __bf16 bf16x2 __attribute__((ext_vector_type(2)));
typedef __bf16 bf16x4 __attribute__((ext_vector_type(4)));
typedef __bf16 bf16x8 __attribute__((ext_vector_type(8)));
typedef float  f32x4  __attribute__((ext_vector_type(4)));

// ---------------- zero cnt: 50000 x 128B lines = 6.4MB = 400000 int4 ----------------
__global__ __launch_bounds__(256) void zero_k(int4* __restrict__ p) {
  int i = blockIdx.x * 256 + threadIdx.x;   // 1563 blocks x 256 = 400128
  if (i < 400000) p[i] = int4{0, 0, 0, 0};
}

// ---- fused {x->bf16, weights->bf16 TRANSPOSED+SWIZZLED, graph boundaries} + {CSR fill} ----
// cnt is PADDED: one counter per 128B cache line (cnt[d*32]). Round-8's packed cnt put
// ~512 serialized same-line L2 atomic RMWs on each of 1563 lines (~40us floor across all
// fill variants); padding cuts that to ~deg (~16) RMWs/line, parallel across L2 channels.
// Blocks 0..6249: conv work. Blocks 6250..9377: 8-class dst-confined CSR fill
// (all writers of a csr/cnt line on one XCD; nt-stores measured WORSE in round 9).
__global__ __launch_bounds__(256) void convfill_k(const float* __restrict__ x,
                                                  bf16* __restrict__ xb,
                                                  const float* __restrict__ w1l, const float* __restrict__ w1r,
                                                  const float* __restrict__ w2l, const float* __restrict__ w2r,
                                                  const float* __restrict__ w3l, const float* __restrict__ w3r,
                                                  bf16* __restrict__ wb,
                                                  const int* __restrict__ batch,
                                                  int* __restrict__ gs,
                                                  const int* __restrict__ src,
                                                  const int* __restrict__ dst,
                                                  int* __restrict__ cnt,
                                                  unsigned short* __restrict__ csr) {
  if (blockIdx.x < 6250) {
    int t = blockIdx.x * 256 + threadIdx.x;   // t < 1,600,000 = NND*CF/4
    {
      f32x4 v = ((const f32x4*)x)[t];
      bf16x4 o;
      o[0] = (bf16)v[0]; o[1] = (bf16)v[1]; o[2] = (bf16)v[2]; o[3] = (bf16)v[3];
      ((bf16x4*)xb)[t] = o;
    }
    if (t < 49152) {  // 6 matrices x 16384 elems, 2 per thread
      int m = t >> 13, w2i = t & 8191;
      const float* sp = (m == 0) ? w1l : (m == 1) ? w1r : (m == 2) ? w2l
                      : (m == 3) ? w2r : (m == 4) ? w3l : w3r;
      int e0 = w2i * 2;
      int k = e0 >> 7, n = e0 & 127;          // source w[k][n], n even
      float2 v = *(const float2*)(sp + e0);
      bf16* wm = wb + m * 16384;
      wm[n * 128       + ((((k >> 3) ^ (n       & 15)) << 3)) + (k & 7)] = (bf16)v.x;
      wm[(n + 1) * 128 + ((((k >> 3) ^ ((n + 1) & 15)) << 3)) + (k & 7)] = (bf16)v.y;
    }
    if (t < NND) {
      int b = batch[t];
      if (t == 0) {
        for (int g = 0; g <= b; g++) gs[g] = 0;
      } else {
        int pb = batch[t - 1];
        for (int g = pb + 1; g <= b; g++) gs[g] = t;
      }
      if (t == NND - 1) {
        for (int g = b + 1; g <= NGR; g++) gs[g] = NND;
      }
    }
  } else {
    int bb = blockIdx.x - 6250;               // 3128 fill blocks = 391 chunks x 8 classes
    int r  = bb & 7;
    int lo = r * 6250, hi = lo + 6250;
    int ebase = (bb >> 3) * 2048;
#pragma unroll
    for (int h = 0; h < 2; h++) {
      int e = ebase + h * 1024 + threadIdx.x * 4;
      if (e < NE) {                            // NE % 4 == 0 -> full int4 in bounds
        int4 d4 = *(const int4*)(dst + e);
        int4 s4 = *(const int4*)(src + e);
        int dd[4] = {d4.x, d4.y, d4.z, d4.w};
        int ss[4] = {s4.x, s4.y, s4.z, s4.w};
#pragma unroll
        for (int u = 0; u < 4; u++) {
          int d = dd[u];
          if (d >= lo && d < hi) {
            int p = atomicAdd(&cnt[d << 5], 1);   // padded: 1 counter / 128B line
            if (p < DCAP) csr[d * DCAP + p] = (unsigned short)ss[u];
          }
        }
      }
    }
  }
}

// ---------------- mean-aggregate: wave = 1 node; 16 lanes x 16B; up to 32 edges in flight ----
__global__ __launch_bounds__(256) void agg_k(const bf16* __restrict__ xin,
                                             const int* __restrict__ cnt,
                                             const unsigned short* __restrict__ csr,
                                             bf16* __restrict__ aggout) {
  int wid  = (blockIdx.x * 256 + threadIdx.x) >> 6;
  int lane = threadIdx.x & 63;
  if (wid >= NND) return;
  int sub = lane >> 4;        // edge slot 0..3
  int c8  = (lane & 15) * 8;  // feature group
  int deg = min(cnt[wid << 5], DCAP);
  int ebase = wid * DCAP;
  float a[8] = {};
  {
    int s[8]; float m[8]; bf16x8 v[8];
#pragma unroll
    for (int u = 0; u < 4; u++) {
      int i = u * 4 + sub;
      s[u] = csr[ebase + ((i < deg) ? i : 0)];
      m[u] = (i < deg) ? 1.f : 0.f;
    }
#pragma unroll
    for (int u = 0; u < 4; u++) v[u] = *(const bf16x8*)(xin + s[u] * 128 + c8);
    if (deg > 16) {  // wave-uniform: issue batch B (edges 16..31) before consuming A
#pragma unroll
      for (int u = 4; u < 8; u++) {
        int i = u * 4 + sub;
        s[u] = csr[ebase + ((i < deg) ? i : 0)];
        m[u] = (i < deg) ? 1.f : 0.f;
      }
#pragma unroll
      for (int u = 4; u < 8; u++) v[u] = *(const bf16x8*)(xin + s[u] * 128 + c8);
    }
#pragma unroll
    for (int u = 0; u < 4; u++)
#pragma unroll
      for (int j = 0; j < 8; j++) a[j] += m[u] * (float)v[u][j];
    if (deg > 16) {
#pragma unroll
      for (int u = 4; u < 8; u++)
#pragma unroll
        for (int j = 0; j < 8; j++) a[j] += m[u] * (float)v[u][j];
    }
  }
  for (int e = 32; e < deg; e += 16) {  // rare tail (deg>32, ~0.02% of nodes)
    int s[4]; float m[4]; bf16x8 v[4];
#pragma unroll
    for (int u = 0; u < 4; u++) {
      int i = e + u * 4 + sub;
      s[u] = csr[ebase + ((i < deg) ? i : 0)];
      m[u] = (i < deg) ? 1.f : 0.f;
    }
#pragma unroll
    for (int u = 0; u < 4; u++) v[u] = *(const bf16x8*)(xin + s[u] * 128 + c8);
#pragma unroll
    for (int u = 0; u < 4; u++)
#pragma unroll
      for (int j = 0; j < 8; j++) a[j] += m[u] * (float)v[u][j];
  }
#pragma unroll
  for (int j = 0; j < 8; j++) {
    a[j] += __shfl_xor(a[j], 16);
    a[j] += __shfl_xor(a[j], 32);
  }
  if (sub == 0) {
    float inv = 1.0f / fmaxf((float)deg, 1.0f);
    bf16x8 o;
#pragma unroll
    for (int j = 0; j < 8; j++) o[j] = (bf16)(a[j] * inv);
    *(bf16x8*)(aggout + wid * 128 + c8) = o;
  }
}

// ---------------- fused [agg|prev] @ [wl;wr] + b, ReLU, (+prev), LayerNorm ----------------
// Block = 256 thr (4 waves) x 64 rows; wave = 16 rows. Two K-phases over a 32KB LDS tile.
// Weights arrive PRE-SWIZZLED from global, staging is a linear 16B memcpy. All 8
// A-fragments prefetched before the first barrier. ~4 blocks/CU resident.
template <typename TO>
__global__ __launch_bounds__(256, 4) void gemm_k(
    const bf16* __restrict__ aggp, const bf16* __restrict__ prev,
    const bf16* __restrict__ wswz,   // 2 matrices (wl,wr), 16384 elems each, pre-swizzled
    const float* __restrict__ bias, const float* __restrict__ gamma,
    const float* __restrict__ beta, TO* __restrict__ outp, int addres) {
  __shared__ bf16 bt[16384];   // 32KB
  int tid = threadIdx.x;
  int lane = tid & 63;
  int wave = tid >> 6;
  int q = lane >> 4, r = lane & 15;
  int wrow = blockIdx.x * 64 + wave * 16;
  int arow = min(wrow + r, NND - 1);   // clamped; OOB rows never stored

  // stage phase-0 tile (wl), linear copy
  {
    const bf16x8* g = (const bf16x8*)wswz;
#pragma unroll
    for (int i = 0; i < 8; i++)
      ((bf16x8*)bt)[tid + i * 256] = g[tid + i * 256];
  }
  // prefetch ALL A-fragments (both phases) while staging settles
  bf16x8 af0[4], af1[4];
  {
    const bf16* a0 = aggp + arow * 128 + q * 8;
    const bf16* a1 = prev + arow * 128 + q * 8;
#pragma unroll
    for (int kk = 0; kk < 4; kk++) af0[kk] = *(const bf16x8*)(a0 + kk * 32);
#pragma unroll
    for (int kk = 0; kk < 4; kk++) af1[kk] = *(const bf16x8*)(a1 + kk * 32);
  }
  __syncthreads();

  f32x4 acc[8] = {};
#pragma unroll
  for (int kk = 0; kk < 4; kk++) {
#pragma unroll
    for (int t = 0; t < 8; t++) {
      int n = t * 16 + r;
      bf16x8 bfrag = *(const bf16x8*)&bt[n * 128 + (((kk * 4 + q) ^ (n & 15)) << 3)];
      acc[t] = __builtin_amdgcn_mfma_f32_16x16x32_bf16(af0[kk], bfrag, acc[t], 0, 0, 0);
    }
  }
  __syncthreads();   // phase-0 readers done
  // stage phase-1 tile (wr)
  {
    const bf16x8* g = (const bf16x8*)(wswz + 16384);
#pragma unroll
    for (int i = 0; i < 8; i++)
      ((bf16x8*)bt)[tid + i * 256] = g[tid + i * 256];
  }
  __syncthreads();
#pragma unroll
  for (int kk = 0; kk < 4; kk++) {
#pragma unroll
    for (int t = 0; t < 8; t++) {
      int n = t * 16 + r;
      bf16x8 bfrag = *(const bf16x8*)&bt[n * 128 + (((kk * 4 + q) ^ (n & 15)) << 3)];
      acc[t] = __builtin_amdgcn_mfma_f32_16x16x32_bf16(af1[kk], bfrag, acc[t], 0, 0, 0);
    }
  }

  float biasf[8], gf[8], bef[8];
#pragma unroll
  for (int t = 0; t < 8; t++) {
    int c = t * 16 + r;
    biasf[t] = bias[c];
    gf[t]    = gamma[c];
    bef[t]   = beta[c];
  }

#pragma unroll
  for (int reg = 0; reg < 4; reg++) {
    int row = wrow + q * 4 + reg;
    int rr  = (row < NND) ? row : (NND - 1);
    const bf16* prow = prev + rr * 128;
    float vals[8];
    float s = 0.f, s2 = 0.f;
#pragma unroll
    for (int t = 0; t < 8; t++) {
      float v = acc[t][reg] + biasf[t];
      v = fmaxf(v, 0.f);
      if (addres) v += (float)prow[t * 16 + r];
      vals[t] = v;
      s += v;
      s2 += v * v;
    }
#pragma unroll
    for (int m = 1; m < 16; m <<= 1) {
      s  += __shfl_xor(s, m);
      s2 += __shfl_xor(s2, m);
    }
    float mean = s * (1.f / 128.f);
    float var  = fmaxf(s2 * (1.f / 128.f) - mean * mean, 0.f);
    float rstd = rsqrtf(var + 1e-5f);
    if (row < NND) {
      TO* orow = outp + row * 128;
#pragma unroll
      for (int t = 0; t < 8; t++)
        orow[t * 16 + r] = (TO)((vals[t] - mean) * rstd * gf[t] + bef[t]);
    }
  }
}

// ---------------- fused mean-pool + head (sorted batch, no atomics) ----------------
__global__ __launch_bounds__(256) void poolhead_k(
    const float* __restrict__ h3, const int* __restrict__ gs,
    const float* __restrict__ wc, const float* __restrict__ bc,
    float* __restrict__ outv, float* __restrict__ avgv) {
  int g = blockIdx.x;
  int s = gs[g], epos = gs[g + 1];
  int tid = threadIdx.x;
  int wave = tid >> 6, lane = tid & 63;
  float a0 = 0.f, a1 = 0.f;
  for (int row = s + wave; row < epos; row += 4) {
    float2 v = *(const float2*)(h3 + row * 128 + 2 * lane);
    a0 += v.x; a1 += v.y;
  }
  __shared__ float red[4][128];
  red[wave][2 * lane]     = a0;
  red[wave][2 * lane + 1] = a1;
  __syncthreads();
  __shared__ float sp[4];
  if (tid < 128) {
    float t4  = red[0][tid] + red[1][tid] + red[2][tid] + red[3][tid];
    float inv = 1.f / fmaxf((float)(epos - s), 1.f);
    float avg = t4 * inv;
    avgv[g * 128 + tid] = avg;
    float p0 = avg * wc[tid * 2 + 0];
    float p1 = avg * wc[tid * 2 + 1];
#pragma unroll
    for (int m = 1; m < 64; m <<= 1) {
      p0 += __shfl_xor(p0, m);
      p1 += __shfl_xor(p1, m);
    }
    if ((tid & 63) == 0) {
      sp[(tid >> 6) * 2]     = p0;
      sp[(tid >> 6) * 2 + 1] = p1;
    }
  }
  __syncthreads();
  if (tid == 0) {
    outv[g * 2 + 0] = sp[0] + sp[2] + bc[0];
    outv[g * 2 + 1] = sp[1] + sp[3] + bc[1];
  }
}

extern "C" void kernel_launch(void* const* d_in, const int* in_sizes, int n_in,
                              void* d_out, int out_size, void* d_ws, size_t ws_size,
                              hipStream_t stream) {
  const float* x   = (const float*)d_in[0];
  const int* ei    = (const int*)d_in[1];
  const int* batch = (const int*)d_in[2];
  const float* w1l = (const float*)d_in[3],  *w1r = (const float*)d_in[4];
  const float* b1  = (const float*)d_in[5],  *g1  = (const float*)d_in[6],  *be1 = (const float*)d_in[7];
  const float* w2l = (const float*)d_in[8],  *w2r = (const float*)d_in[9];
  const float* b2  = (const float*)d_in[10], *g2  = (const float*)d_in[11], *be2 = (const float*)d_in[12];
  const float* w3l = (const float*)d_in[13], *w3r = (const float*)d_in[14];
  const float* b3  = (const float*)d_in[15], *g3  = (const float*)d_in[16], *be3 = (const float*)d_in[17];
  const float* wc  = (const float*)d_in[18], *bc  = (const float*)d_in[19];
  const int* srcv = ei;
  const int* dstv = ei + NE;

  char* base = (char*)d_ws;
  int*            cnt  = (int*)(base + 0);            // 6.4MB: 1 counter / 128B line (cnt[d*32])
  int*            gs   = (int*)(base + 6400000);      // 2052
  bf16*           wb   = (bf16*)(base + 6403072);     // 196608 (6 x 128x128 bf16, pre-swizzled)
  unsigned short* csr  = (unsigned short*)(base + 6599680);  // 6.4 MB (50000 x 64 u16 slots)
  bf16*           agg  = (bf16*)(base + 13000704);    // 12.8 MB
  bf16*           h1   = (bf16*)(base + 25800704);    // 12.8 MB
  bf16*           h2xb = (bf16*)(base + 38600704);    // 12.8 MB: xb until gemm1, then h2

  float* outv = (float*)d_out;             // 1024
  float* h3   = outv + 1024;               // 50000*128
  float* avgv = outv + 1024 + NND * CF;    // 512*128

  zero_k<<<1563, 256, 0, stream>>>((int4*)base);
  convfill_k<<<9378, 256, 0, stream>>>(x, h2xb, w1l, w1r, w2l, w2r, w3l, w3r, wb,
                                       batch, gs, srcv, dstv, cnt, csr);

  // layer 1 (xb aliases h2xb; dead after gemm1 consumes it)
  agg_k<<<12500, 256, 0, stream>>>(h2xb, cnt, csr, agg);
  gemm_k<bf16><<<782, 256, 0, stream>>>(agg, h2xb, wb,           b1, g1, be1, h1, 0);
  // layer 2
  agg_k<<<12500, 256, 0, stream>>>(h1, cnt, csr, agg);
  gemm_k<bf16><<<782, 256, 0, stream>>>(agg, h1, wb + 2 * 16384, b2, g2, be2, h2xb, 1);
  // layer 3
  agg_k<<<12500, 256, 0, stream>>>(h2xb, cnt, csr, agg);
  gemm_k<float><<<782, 256, 0, stream>>>(agg, h2xb, wb + 4 * 16384, b3, g3, be3, h3, 1);
  // pool + head
  poolhead_k<<<NGR, 256, 0, stream>>>(h3, gs, wc, bc, outv, avgv);
}